// Round 10
// baseline (19.016 us; speedup 1.0000x reference)
//
#include <hip/hip_runtime.h>

#define HW_BIG   1e10f
#define LOSS_EPS 1e-8f

typedef unsigned long long u64;

// ---------------------------------------------------------------------------
// Branchless nearest-set-bit distance from a register-resident 256-bit row
// mask (w0..w3) to position y. Returns >255 if the row is empty. Exact.
// ---------------------------------------------------------------------------
__device__ __forceinline__ int row_nearest_reg(u64 w0, u64 w1, u64 w2, u64 w3,
                                               int y) {
    const int yw = y >> 6, yb = y & 63;
    const u64 lowm  = (~0ULL) >> (63 - yb);   // bits [0..yb]
    const u64 highm = (~0ULL) << yb;          // bits [yb..63]
    // highest set bit at position <= y
    u64 d0 = (yw == 0) ? (w0 & lowm) : w0;
    u64 d1 = (yw < 1) ? 0ULL : ((yw == 1) ? (w1 & lowm) : w1);
    u64 d2 = (yw < 2) ? 0ULL : ((yw == 2) ? (w2 & lowm) : w2);
    u64 d3 = (yw < 3) ? 0ULL : ((yw == 3) ? (w3 & lowm) : w3);
    int hb = -32768;
    hb = d0 ? (63  - __builtin_clzll(d0)) : hb;
    hb = d1 ? (127 - __builtin_clzll(d1)) : hb;
    hb = d2 ? (191 - __builtin_clzll(d2)) : hb;
    hb = d3 ? (255 - __builtin_clzll(d3)) : hb;
    const int dn = y - hb;                    // >255 if empty below
    // lowest set bit at position >= y
    u64 u0 = (yw == 0) ? (w0 & highm) : 0ULL;
    u64 u1 = (yw == 1) ? (w1 & highm) : ((yw < 1) ? w1 : 0ULL);
    u64 u2 = (yw == 2) ? (w2 & highm) : ((yw < 2) ? w2 : 0ULL);
    u64 u3 = (yw == 3) ? (w3 & highm) : ((yw < 3) ? w3 : 0ULL);
    int ls = 32768 + y;
    ls = u3 ? (192 + (int)__builtin_ctzll(u3)) : ls;
    ls = u2 ? (128 + (int)__builtin_ctzll(u2)) : ls;
    ls = u1 ? (64  + (int)__builtin_ctzll(u1)) : ls;
    ls = u0 ? ((int)__builtin_ctzll(u0))       : ls;
    const int up = ls - y;                    // >255 if empty above
    return min(dn, up);
}

// ---------------------------------------------------------------------------
// Kernel 1: vectorized streaming mask builder. 256 thr/block, 4 px/thread
// via float4; nibble-pack into u64 words with a 4-step __shfl_xor OR-reduce.
// Word layout: flat word index = pixel_index >> 6 (bit b = pixel 64w+b).
// ---------------------------------------------------------------------------
__global__ void k_masks(const float* __restrict__ inp,
                        const float* __restrict__ tgt,
                        u64* __restrict__ mv,
                        u64* __restrict__ ml) {
    const int t = threadIdx.x;
    const size_t gid4 = (size_t)blockIdx.x * 256 + t;
    const float4 v4 = reinterpret_cast<const float4*>(inp)[gid4];
    const float4 t4 = reinterpret_cast<const float4*>(tgt)[gid4];
    const unsigned nv = (unsigned)(v4.x > 0.0f) | ((unsigned)(v4.y > 0.0f) << 1)
                      | ((unsigned)(v4.z > 0.0f) << 2) | ((unsigned)(v4.w > 0.0f) << 3);
    const unsigned nt = (unsigned)(t4.x > 0.5f) | ((unsigned)(t4.y > 0.5f) << 1)
                      | ((unsigned)(t4.z > 0.5f) << 2) | ((unsigned)(t4.w > 0.5f) << 3);
    const int sh = (t & 15) * 4;
    u64 wv_ = ((u64)nv) << sh;
    u64 wt_ = ((u64)nt) << sh;
#pragma unroll
    for (int off = 1; off < 16; off <<= 1) {
        wv_ |= (u64)__shfl_xor((long long)wv_, off, 64);
        wt_ |= (u64)__shfl_xor((long long)wt_, off, 64);
    }
    if ((t & 15) == 0) {
        mv[gid4 >> 4] = wv_;
        ml[gid4 >> 4] = wt_;
    }
}

// ---------------------------------------------------------------------------
// Kernel 2 (boundary + DT + loss, 8 y-rows/block): block = (img, 8 y-rows),
// 1024 threads = (x = tid>>2, yq = tid&3); pixels (x,y0+yq) and (x,y0+yq+4).
// Stage whole-image mask words -> boundary words in LDS (word-parallel,
// bit-exact) -> row masks into REGISTERS -> branchless row_nearest ->
// G (float2, padded) in LDS -> strip-mined clamp-indexed early-exit scan ->
// fused weight + focal BCE -> deterministic 16-wave reduction.
// ---------------------------------------------------------------------------
__global__ void k_dt_loss(const float* __restrict__ inp,
                          const u64* __restrict__ mv,
                          const u64* __restrict__ ml,
                          float* __restrict__ partials) {
    __shared__ u64 Mv[1024];        // [row x][yword] predicted-mask bits
    __shared__ u64 Ml[1024];        // label-mask bits
    __shared__ u64 Bib[1024];       // predicted-image boundary bits
    __shared__ u64 Blb[1024];       // label boundary bits
    __shared__ float2 GG[256][10];  // (g_ib, g_lb) indexed [x'][yr], padded
    __shared__ float wsum[16];
    const int tid = threadIdx.x;
    const int img = blockIdx.x >> 5;
    const int y0  = (blockIdx.x & 31) * 8;
    const int x   = tid >> 2;           // 0..255
    const int yq  = tid & 3;            // 0..3
    const int ya  = y0 + yq;
    const int yv  = ya + 4;

    const size_t mbase = (size_t)img * 1024;
    Mv[tid] = mv[mbase + tid];
    Ml[tid] = ml[mbase + tid];
    const float va = inp[((size_t)img * 256 + x) * 256 + ya];
    const float vb = inp[((size_t)img * 256 + x) * 256 + yv];
    __syncthreads();

    // boundary words (zero-padded 4-neighbor rule), bit-exact as before
    {
        const int xr_ = tid >> 2, j = tid & 3;
        u64 own = Mv[tid];
        u64 up  = (xr_ > 0)   ? Mv[tid - 4] : 0ULL;
        u64 dn  = (xr_ < 255) ? Mv[tid + 4] : 0ULL;
        u64 lf  = (own << 1) | ((j > 0) ? (Mv[tid - 1] >> 63) : 0ULL);
        u64 rt  = (own >> 1) | ((j < 3) ? (Mv[tid + 1] << 63) : 0ULL);
        Bib[tid] = own & ~(up & dn & lf & rt);
        own = Ml[tid];
        up  = (xr_ > 0)   ? Ml[tid - 4] : 0ULL;
        dn  = (xr_ < 255) ? Ml[tid + 4] : 0ULL;
        lf  = (own << 1) | ((j > 0) ? (Ml[tid - 1] >> 63) : 0ULL);
        rt  = (own >> 1) | ((j < 3) ? (Ml[tid + 1] << 63) : 0ULL);
        Blb[tid] = own & ~(up & dn & lf & rt);
    }
    __syncthreads();

    // row masks into registers (quad-broadcast LDS reads, one latency window)
    const u64 b0 = Bib[x * 4 + 0], b1 = Bib[x * 4 + 1];
    const u64 b2 = Bib[x * 4 + 2], b3 = Bib[x * 4 + 3];
    const u64 l0 = Blb[x * 4 + 0], l1 = Blb[x * 4 + 1];
    const u64 l2 = Blb[x * 4 + 2], l3 = Blb[x * 4 + 3];
    const int yw = ya >> 6;            // ya and yv share the same word
    const u64 mlw = Ml[x * 4 + yw];
    const int yba = ya & 63, ybb = yv & 63;
    const u64 bw = (yw == 0) ? b0 : (yw == 1) ? b1 : (yw == 2) ? b2 : b3;
    const u64 lw = (yw == 0) ? l0 : (yw == 1) ? l1 : (yw == 2) ? l2 : l3;
    const bool fibA = (bw >> yba) & 1, fibB = (bw >> ybb) & 1;
    const bool flbA = (lw >> yba) & 1, flbB = (lw >> ybb) & 1;
    const float tA = ((mlw >> yba) & 1) ? 1.0f : 0.0f;
    const float tB = ((mlw >> ybb) & 1) ? 1.0f : 0.0f;

    const int d1a = row_nearest_reg(b0, b1, b2, b3, ya);
    const int d2a = row_nearest_reg(l0, l1, l2, l3, ya);
    const int d1b = row_nearest_reg(b0, b1, b2, b3, yv);
    const int d2b = row_nearest_reg(l0, l1, l2, l3, yv);
    const float g1a = (d1a > 255) ? HW_BIG : (float)(d1a * d1a);
    const float g2a = (d2a > 255) ? HW_BIG : (float)(d2a * d2a);
    const float g1b = (d1b > 255) ? HW_BIG : (float)(d1b * d1b);
    const float g2b = (d2b > 255) ? HW_BIG : (float)(d2b * d2b);
    GG[x][yq]     = make_float2(g1a, g2a);
    GG[x][yq + 4] = make_float2(g1b, g2b);
    __syncthreads();

    // strip-mined exact early-exit outward scan over x' = x -+ d.
    // Clamped indices are exact (clamped candidate >= an already-considered
    // one); extra strip iterations only add valid candidates.
    float m1a = flbA ? g1a : 0.0f;
    float m2a = fibA ? g2a : 0.0f;
    float m1b = flbB ? g1b : 0.0f;
    float m2b = fibB ? g2b : 0.0f;
    float mm = fmaxf(fmaxf(m1a, m2a), fmaxf(m1b, m2b));
    for (int d = 1; d < 256; d += 4) {
        if ((float)(d * d) >= mm) break;
#pragma unroll
        for (int k = 0; k < 4; ++k) {
            const int dd = d + k;
            const float fd2 = (float)(dd * dd);    // exact integer in f32
            const int xl = (x - dd > 0) ? (x - dd) : 0;
            const int xr = (x + dd < 255) ? (x + dd) : 255;
            const float2 glA = GG[xl][yq];
            const float2 grA = GG[xr][yq];
            const float2 glB = GG[xl][yq + 4];
            const float2 grB = GG[xr][yq + 4];
            m1a = fminf(fminf(m1a, glA.x + fd2), grA.x + fd2);
            m2a = fminf(fminf(m2a, glA.y + fd2), grA.y + fd2);
            m1b = fminf(fminf(m1b, glB.x + fd2), grB.x + fd2);
            m2b = fminf(fminf(m2b, glB.y + fd2), grB.y + fd2);
        }
        mm = fmaxf(fmaxf(m1a, m2a), fmaxf(m1b, m2b));
    }

    // fused weight + focal BCE (GAMMA=1, THETA=1, SIGMA=1), fast intrinsics
    const float pa = 1.0f / (1.0f + __expf(-va));
    float wA = 1.0f;
    if (flbA) wA += __expf(-sqrtf(m1a));
    if (fibA) wA += __expf(-sqrtf(m2a));
    float lossA = wA * (-(1.0f - pa) * tA * __logf(pa + LOSS_EPS)
                        - pa * (1.0f - tA) * __logf(1.0f - pa + LOSS_EPS));

    const float pb = 1.0f / (1.0f + __expf(-vb));
    float wB = 1.0f;
    if (flbB) wB += __expf(-sqrtf(m1b));
    if (fibB) wB += __expf(-sqrtf(m2b));
    float lossB = wB * (-(1.0f - pb) * tB * __logf(pb + LOSS_EPS)
                        - pb * (1.0f - tB) * __logf(1.0f - pb + LOSS_EPS));

    // deterministic block reduction: wave shfl tree + 16 wave partials
    float s = lossA + lossB;
#pragma unroll
    for (int off = 32; off > 0; off >>= 1) s += __shfl_down(s, off, 64);
    if ((tid & 63) == 0) wsum[tid >> 6] = s;
    __syncthreads();
    if (tid == 0) {
        float bs = 0.0f;
#pragma unroll
        for (int i = 0; i < 16; ++i) bs += wsum[i];
        partials[blockIdx.x] = bs;
    }
}

// ---------------------------------------------------------------------------
// Kernel 3: reduce partials -> mean (single block, fixed order, double accum)
// ---------------------------------------------------------------------------
__global__ void k_reduce(const float* __restrict__ partials, int n,
                         float* __restrict__ out, double inv_count) {
    __shared__ double sw[4];
    const int tid = threadIdx.x;
    double s = 0.0;
    for (int i = tid; i < n; i += 256) s += (double)partials[i];
#pragma unroll
    for (int off = 32; off > 0; off >>= 1) s += __shfl_down(s, off, 64);
    const int lane = tid & 63, wv = tid >> 6;
    if (lane == 0) sw[wv] = s;
    __syncthreads();
    if (tid == 0) out[0] = (float)(((sw[0] + sw[1]) + (sw[2] + sw[3])) * inv_count);
}

// ---------------------------------------------------------------------------
extern "C" void kernel_launch(void* const* d_in, const int* in_sizes, int n_in,
                              void* d_out, int out_size, void* d_ws, size_t ws_size,
                              hipStream_t stream) {
    const float* inp = (const float*)d_in[0];
    const float* tgt = (const float*)d_in[1];
    float* out = (float*)d_out;

    const int total = in_sizes[0];          // B*256*256
    const int nimg  = total / 65536;        // B = 8
    const int nblk1 = total / 1024;         // 512 blocks (masks, 4 px/thread)
    const int nblk2 = nimg * 32;            // 256 blocks (DT+loss, 8 rows each)

    char* ws = (char*)d_ws;
    u64*   mv    = (u64*)ws;                          // nimg*1024 u64 each
    u64*   ml    = mv + (size_t)nimg * 1024;
    float* parts = (float*)(ml + (size_t)nimg * 1024);

    k_masks  <<<nblk1, 256,  0, stream>>>(inp, tgt, mv, ml);
    k_dt_loss<<<nblk2, 1024, 0, stream>>>(inp, mv, ml, parts);
    k_reduce <<<1,     256,  0, stream>>>(parts, nblk2, out, 1.0 / (double)total);
}

// Round 11
// 17.005 us; speedup vs baseline: 1.1183x; 1.1183x over previous
//
#include <hip/hip_runtime.h>

#define HW_BIG   1e10f
#define LOSS_EPS 1e-8f

typedef unsigned long long u64;

// ---------------------------------------------------------------------------
// distance (in pixels) to nearest set bit in a 256-bit row mask rm[4] from
// position y. Returns 32768 if the row is empty. Exact. While-loops almost
// never iterate on dense masks (first word hit is the common case).
// ---------------------------------------------------------------------------
__device__ __forceinline__ int row_nearest(const u64* rm, int y) {
    const int yw = y >> 6, yb = y & 63;
    int dd = 32768;
    u64 w = rm[yw] & (~0ULL >> (63 - yb));
    int j = yw;
    while (w == 0 && j > 0) w = rm[--j];
    if (w) dd = y - (j * 64 + 63 - __builtin_clzll(w));
    u64 w2 = rm[yw] & (~0ULL << yb);
    int j2 = yw;
    while (w2 == 0 && j2 < 3) w2 = rm[++j2];
    if (w2) { int du = (j2 * 64 + __builtin_ctzll(w2)) - y; dd = min(dd, du); }
    return dd;
}

// ---------------------------------------------------------------------------
// Kernel 1: vectorized streaming mask builder. 256 thr/block, 4 px/thread
// via float4; nibble-pack into u64 words with a 4-step __shfl_xor OR-reduce.
// Word layout: flat word index = pixel_index >> 6 (bit b = pixel 64w+b).
// ---------------------------------------------------------------------------
__global__ void k_masks(const float* __restrict__ inp,
                        const float* __restrict__ tgt,
                        u64* __restrict__ mv,
                        u64* __restrict__ ml) {
    const int t = threadIdx.x;
    const size_t gid4 = (size_t)blockIdx.x * 256 + t;
    const float4 v4 = reinterpret_cast<const float4*>(inp)[gid4];
    const float4 t4 = reinterpret_cast<const float4*>(tgt)[gid4];
    const unsigned nv = (unsigned)(v4.x > 0.0f) | ((unsigned)(v4.y > 0.0f) << 1)
                      | ((unsigned)(v4.z > 0.0f) << 2) | ((unsigned)(v4.w > 0.0f) << 3);
    const unsigned nt = (unsigned)(t4.x > 0.5f) | ((unsigned)(t4.y > 0.5f) << 1)
                      | ((unsigned)(t4.z > 0.5f) << 2) | ((unsigned)(t4.w > 0.5f) << 3);
    const int sh = (t & 15) * 4;
    u64 wv_ = ((u64)nv) << sh;
    u64 wt_ = ((u64)nt) << sh;
#pragma unroll
    for (int off = 1; off < 16; off <<= 1) {
        wv_ |= (u64)__shfl_xor((long long)wv_, off, 64);
        wt_ |= (u64)__shfl_xor((long long)wt_, off, 64);
    }
    if ((t & 15) == 0) {
        mv[gid4 >> 4] = wv_;
        ml[gid4 >> 4] = wt_;
    }
}

// ---------------------------------------------------------------------------
// Kernel 2 (boundary + DT + loss, 8 y-rows/block): block = (img, 8 y-rows),
// 1024 threads = (x = tid>>2, yq = tid&3); pixels (x,y0+yq) and (x,y0+yq+4).
// Stage whole-image mask words -> boundary words in LDS (word-parallel,
// bit-exact) -> while-loop row_nearest (cheap common case) -> G[256][9]
// padded (2-way bank aliasing = free) -> MERGED A/B early-exit outward scan
// (one loop, shared break; length = max not sum) -> fused weight + focal BCE
// (fast __expf/__logf) -> deterministic 16-wave reduction.
// ---------------------------------------------------------------------------
__global__ void k_dt_loss(const float* __restrict__ inp,
                          const u64* __restrict__ mv,
                          const u64* __restrict__ ml,
                          float* __restrict__ partials) {
    __shared__ u64 Mv[1024];       // [row x][yword] predicted-mask bits
    __shared__ u64 Ml[1024];       // label-mask bits
    __shared__ u64 Bib[1024];      // predicted-image boundary bits
    __shared__ u64 Blb[1024];      // label boundary bits
    __shared__ float G1[256][9];   // g_ib indexed [x'][yr], padded (9)
    __shared__ float G2[256][9];   // g_lb
    __shared__ float wsum[16];
    const int tid = threadIdx.x;
    const int img = blockIdx.x >> 5;
    const int y0  = (blockIdx.x & 31) * 8;
    const int x   = tid >> 2;           // 0..255
    const int yq  = tid & 3;            // 0..3
    const int ya  = y0 + yq;
    const int yv  = ya + 4;

    const size_t mbase = (size_t)img * 1024;
    Mv[tid] = mv[mbase + tid];
    Ml[tid] = ml[mbase + tid];
    // 4 consecutive lanes read 16 contiguous bytes (x uniform per lane quad)
    const float va = inp[((size_t)img * 256 + x) * 256 + ya];
    const float vb = inp[((size_t)img * 256 + x) * 256 + yv];
    __syncthreads();

    // boundary words (zero-padded 4-neighbor rule), bit-exact
    {
        const int xr_ = tid >> 2, j = tid & 3;
        u64 own = Mv[tid];
        u64 up  = (xr_ > 0)   ? Mv[tid - 4] : 0ULL;
        u64 dn  = (xr_ < 255) ? Mv[tid + 4] : 0ULL;
        u64 lf  = (own << 1) | ((j > 0) ? (Mv[tid - 1] >> 63) : 0ULL);
        u64 rt  = (own >> 1) | ((j < 3) ? (Mv[tid + 1] << 63) : 0ULL);
        Bib[tid] = own & ~(up & dn & lf & rt);
        own = Ml[tid];
        up  = (xr_ > 0)   ? Ml[tid - 4] : 0ULL;
        dn  = (xr_ < 255) ? Ml[tid + 4] : 0ULL;
        lf  = (own << 1) | ((j > 0) ? (Ml[tid - 1] >> 63) : 0ULL);
        rt  = (own >> 1) | ((j < 3) ? (Ml[tid + 1] << 63) : 0ULL);
        Blb[tid] = own & ~(up & dn & lf & rt);
    }
    __syncthreads();

    const int ywa = ya >> 6, yba = ya & 63;
    const int ywb = yv >> 6, ybb = yv & 63;
    const bool fibA = (Bib[x * 4 + ywa] >> yba) & 1;
    const bool flbA = (Blb[x * 4 + ywa] >> yba) & 1;
    const float tA  = ((Ml[x * 4 + ywa] >> yba) & 1) ? 1.0f : 0.0f;
    const bool fibB = (Bib[x * 4 + ywb] >> ybb) & 1;
    const bool flbB = (Blb[x * 4 + ywb] >> ybb) & 1;
    const float tB  = ((Ml[x * 4 + ywb] >> ybb) & 1) ? 1.0f : 0.0f;

    const int d1a = row_nearest(&Bib[x * 4], ya);
    const int d2a = row_nearest(&Blb[x * 4], ya);
    const int d1b = row_nearest(&Bib[x * 4], yv);
    const int d2b = row_nearest(&Blb[x * 4], yv);
    const float g1a = (d1a > 255) ? HW_BIG : (float)(d1a * d1a);
    const float g2a = (d2a > 255) ? HW_BIG : (float)(d2a * d2a);
    const float g1b = (d1b > 255) ? HW_BIG : (float)(d1b * d1b);
    const float g2b = (d2b > 255) ? HW_BIG : (float)(d2b * d2b);
    G1[x][yq]     = g1a;
    G2[x][yq]     = g2a;
    G1[x][yq + 4] = g1b;
    G2[x][yq + 4] = g2b;
    __syncthreads();

    // merged exact early-exit outward scan over x' = x -+ d for BOTH pixels.
    // Lanes that don't consume a distance (m1 used only where flb, m2 where
    // fib) init to 0 so they never prolong the scan. Break when d^2 >= all 4.
    float m1a = flbA ? g1a : 0.0f;
    float m2a = fibA ? g2a : 0.0f;
    float m1b = flbB ? g1b : 0.0f;
    float m2b = fibB ? g2b : 0.0f;
    for (int d = 1; d < 256; ++d) {
        const float fd2 = (float)(d * d);          // exact integer in f32
        if (fd2 >= m1a && fd2 >= m2a && fd2 >= m1b && fd2 >= m2b) break;
        const int xl = x - d;
        if (xl >= 0) {
            m1a = fminf(m1a, G1[xl][yq] + fd2);
            m2a = fminf(m2a, G2[xl][yq] + fd2);
            m1b = fminf(m1b, G1[xl][yq + 4] + fd2);
            m2b = fminf(m2b, G2[xl][yq + 4] + fd2);
        }
        const int xr = x + d;
        if (xr < 256) {
            m1a = fminf(m1a, G1[xr][yq] + fd2);
            m2a = fminf(m2a, G2[xr][yq] + fd2);
            m1b = fminf(m1b, G1[xr][yq + 4] + fd2);
            m2b = fminf(m2b, G2[xr][yq + 4] + fd2);
        }
    }

    // fused weight + focal BCE (GAMMA=1, THETA=1, SIGMA=1), fast intrinsics
    const float pa = 1.0f / (1.0f + __expf(-va));
    float wA = 1.0f;
    if (flbA) wA += __expf(-sqrtf(m1a));
    if (fibA) wA += __expf(-sqrtf(m2a));
    float lossA = wA * (-(1.0f - pa) * tA * __logf(pa + LOSS_EPS)
                        - pa * (1.0f - tA) * __logf(1.0f - pa + LOSS_EPS));

    const float pb = 1.0f / (1.0f + __expf(-vb));
    float wB = 1.0f;
    if (flbB) wB += __expf(-sqrtf(m1b));
    if (fibB) wB += __expf(-sqrtf(m2b));
    float lossB = wB * (-(1.0f - pb) * tB * __logf(pb + LOSS_EPS)
                        - pb * (1.0f - tB) * __logf(1.0f - pb + LOSS_EPS));

    // deterministic block reduction: wave shfl tree + 16 wave partials
    float s = lossA + lossB;
#pragma unroll
    for (int off = 32; off > 0; off >>= 1) s += __shfl_down(s, off, 64);
    if ((tid & 63) == 0) wsum[tid >> 6] = s;
    __syncthreads();
    if (tid == 0) {
        float bs = 0.0f;
#pragma unroll
        for (int i = 0; i < 16; ++i) bs += wsum[i];
        partials[blockIdx.x] = bs;
    }
}

// ---------------------------------------------------------------------------
// Kernel 3: reduce partials -> mean (single block, fixed order, double accum)
// ---------------------------------------------------------------------------
__global__ void k_reduce(const float* __restrict__ partials, int n,
                         float* __restrict__ out, double inv_count) {
    __shared__ double sw[4];
    const int tid = threadIdx.x;
    double s = 0.0;
    for (int i = tid; i < n; i += 256) s += (double)partials[i];
#pragma unroll
    for (int off = 32; off > 0; off >>= 1) s += __shfl_down(s, off, 64);
    const int lane = tid & 63, wv = tid >> 6;
    if (lane == 0) sw[wv] = s;
    __syncthreads();
    if (tid == 0) out[0] = (float)(((sw[0] + sw[1]) + (sw[2] + sw[3])) * inv_count);
}

// ---------------------------------------------------------------------------
extern "C" void kernel_launch(void* const* d_in, const int* in_sizes, int n_in,
                              void* d_out, int out_size, void* d_ws, size_t ws_size,
                              hipStream_t stream) {
    const float* inp = (const float*)d_in[0];
    const float* tgt = (const float*)d_in[1];
    float* out = (float*)d_out;

    const int total = in_sizes[0];          // B*256*256
    const int nimg  = total / 65536;        // B = 8
    const int nblk1 = total / 1024;         // 512 blocks (masks, 4 px/thread)
    const int nblk2 = nimg * 32;            // 256 blocks (DT+loss, 8 rows each)

    char* ws = (char*)d_ws;
    u64*   mv    = (u64*)ws;                          // nimg*1024 u64 each
    u64*   ml    = mv + (size_t)nimg * 1024;
    float* parts = (float*)(ml + (size_t)nimg * 1024);

    k_masks  <<<nblk1, 256,  0, stream>>>(inp, tgt, mv, ml);
    k_dt_loss<<<nblk2, 1024, 0, stream>>>(inp, mv, ml, parts);
    k_reduce <<<1,     256,  0, stream>>>(parts, nblk2, out, 1.0 / (double)total);
}